// Round 11
// baseline (1320.515 us; speedup 1.0000x reference)
//
#include <hip/hip_runtime.h>

#define BATCH 16
#define NP1 4096
#define NP2 2048
#define NP3 1024

typedef float v2f __attribute__((ext_vector_type(2)));

// IEEE ops that the compiler may NOT contract/reorder — used for every distance
// that feeds a discrete decision (kNN membership, FPS argmax). Order matches the
// reference: norms (x*x+y*y)+z*z ; knn d = (ni+nj) - 2*dot ; fps d = (dx^2+dy^2)+dz^2.
__device__ __forceinline__ float f_add(float a, float b) { return __fadd_rn(a, b); }
__device__ __forceinline__ float f_mul(float a, float b) { return __fmul_rn(a, b); }
__device__ __forceinline__ float f_sub(float a, float b) { return __fsub_rn(a, b); }
__device__ __forceinline__ float sqnorm3(float x, float y, float z) {
  return f_add(f_add(f_mul(x, x), f_mul(y, y)), f_mul(z, z));
}

__device__ __forceinline__ unsigned long long u64max(unsigned long long a,
                                                     unsigned long long b) {
  return a > b ? a : b;
}
__device__ __forceinline__ unsigned long long u64min(unsigned long long a,
                                                     unsigned long long b) {
  return a < b ? a : b;
}
__device__ __forceinline__ double dmax(double a, double b) { return __builtin_fmax(a, b); }
__device__ __forceinline__ double dmin(double a, double b) { return __builtin_fmin(a, b); }

template<int CTRL, int RMASK>
__device__ __forceinline__ unsigned long long dpp_u64(unsigned long long k) {
  const int lo = __builtin_amdgcn_update_dpp(0, (int)(unsigned)k, CTRL, RMASK, 0xF, true);
  const int hi = __builtin_amdgcn_update_dpp(0, (int)(unsigned)(k >> 32), CTRL, RMASK, 0xF, true);
  return ((unsigned long long)(unsigned)hi << 32) | (unsigned)lo;
}
template<int CTRL, int RMASK>
__device__ __forceinline__ double dpp_dbl(double v) {
  return __longlong_as_double(
      (long long)dpp_u64<CTRL, RMASK>((unsigned long long)__double_as_longlong(v)));
}

// FPS keys: u64 {dist_bits(32) | ILO(32)} reinterpreted as f64. dist_bits ≤
// 0x40400000 and sign bit 0 -> positive f64, never NaN/Inf, so u64 order ==
// f64 order exactly and v_max_f64/v_min_f64 implement exact key compares.
// ILO = ~gi resolves dist-ties to the LOWEST original index (jnp.argmax).
// All keys are > 0 (ILO never 0), so 0.0 is the reduce identity.

// Exact top-2 tuple combine: (a1,a2) := top2({a1,a2} ∪ {b1,b2}).
// Requires a1>=a2, b1>=b2 (and (0,0) acts as identity for positive keys).
__device__ __forceinline__ void tup_comb(double& a1, double& a2, double b1, double b2) {
  const double hi = dmax(a1, b1);
  const double lo = dmin(a1, b1);
  a2 = dmax(lo, dmax(a2, b2));
  a1 = hi;
}
template<int CTRL, int RMASK>
__device__ __forceinline__ void tup_stage(double& a1, double& a2) {
  const double b1 = dpp_dbl<CTRL, RMASK>(a1);
  const double b2 = dpp_dbl<CTRL, RMASK>(a2);
  tup_comb(a1, a2, b1, b2);
}

// ---------------- FPS device block: exact replica of the reference scan, with
// exact 2-per-step speculation (round-3 form: the cheap "untouched" check).
// Per step: global top-2 (G1,G2) from per-wave exact top-2 tuple slots.
// w1=G1 selected; if d_rn(w2,w1) >= min_d(w2) (updates only lower keys; keys
// unique) then w2=G2 is provably the NEXT argmax too -> commit both, apply both
// min-updates sequentially (exact). All DPP reduce trees combine disjoint
// lane/slot windows, so tuple top-2 stays exact.
// Slot tree: each lane reads slot(lane&7) AND slot((lane&7)^1) — 8 distinct
// CONTIGUOUS 16B addresses each (statically bank-conflict-free; the
// data-dependent gather/staging variants of rounds 6/7/9 all regressed) —
// pre-combines, then a 2-stage DPP tuple tree (s->s^2, s->s^4) yields the
// exact global top-2 in every lane.
// fps2 of the network is the identity permutation (journal proof).
// NOTE: this FPS structure is at its measured practical floor (rounds 4-9
// probes); do not restructure without strong new evidence.
template<int N, int M>
__device__ void fps_block(char* __restrict__ smem, const float* __restrict__ P,
                          int* __restrict__ samp, float* __restrict__ pos_out)
{
#pragma clang fp contract(off)
  constexpr int THREADS = 512;
  constexpr int E = N / THREADS;
  constexpr int P2 = E / 2;
  float4* pos4 = (float4*)smem;                                   // [N] by orig idx
  unsigned short* ord = (unsigned short*)(smem + 16 * N);         // [N]
  int* sampL = (int*)(smem + 18 * N);                             // [M]
  unsigned* cursor = (unsigned*)(smem + 18 * N + 4 * M);          // [8]
  double* kslots = (double*)(smem + 18 * N + 4 * M + 32);         // [2][8] double2
  const int tid = threadIdx.x;
  const int lane = tid & 63, wv = tid >> 6;
  const int myslot = lane & 7;
  if (tid < 8) cursor[tid] = 0u;
  __syncthreads();
  int oct[E];
#pragma unroll
  for (int e = 0; e < E; ++e) {
    const int t = e * THREADS + tid;
    const float x = P[t * 3], y = P[t * 3 + 1], z = P[t * 3 + 2];
    pos4[t] = make_float4(x, y, z, 0.f);
    oct[e] = (x > 0.5f ? 1 : 0) | (y > 0.5f ? 2 : 0) | (z > 0.5f ? 4 : 0);
    atomicAdd(&cursor[oct[e]], 1u);
  }
  __syncthreads();
  if (tid == 0) {
    unsigned run = 0;
#pragma unroll
    for (int o = 0; o < 8; ++o) { const unsigned c = cursor[o]; cursor[o] = run; run += c; }
  }
  __syncthreads();
#pragma unroll
  for (int e = 0; e < E; ++e) {
    const unsigned d = atomicAdd(&cursor[oct[e]], 1u);
    ord[d] = (unsigned short)(e * THREADS + tid);
  }
  __syncthreads();
  const float4 p0 = pos4[0];
  const float x0 = p0.x, y0 = p0.y, z0 = p0.z;
  v2f X2[P2], Y2[P2], Z2[P2], MD2[P2];
  unsigned ILO[E];
  float mnx = 1e30f, mny = 1e30f, mnz = 1e30f;
  float mxx = -1e30f, mxy = -1e30f, mxz = -1e30f;
  {
    const v2f x0v = {x0, x0}, y0v = {y0, y0}, z0v = {z0, z0};
#pragma unroll
    for (int p = 0; p < P2; ++p) {
      const int q0 = wv * (64 * E) + (2 * p) * 64 + lane;  // wave-contiguous sorted range
      const int o0 = ord[q0], o1 = ord[q0 + 64];
      const float4 a0 = pos4[o0], a1 = pos4[o1];
      X2[p] = (v2f){a0.x, a1.x}; Y2[p] = (v2f){a0.y, a1.y}; Z2[p] = (v2f){a0.z, a1.z};
      mnx = fminf(mnx, fminf(a0.x, a1.x)); mxx = fmaxf(mxx, fmaxf(a0.x, a1.x));
      mny = fminf(mny, fminf(a0.y, a1.y)); mxy = fmaxf(mxy, fmaxf(a0.y, a1.y));
      mnz = fminf(mnz, fminf(a0.z, a1.z)); mxz = fmaxf(mxz, fmaxf(a0.z, a1.z));
      const v2f dx = X2[p] - x0v, dy = Y2[p] - y0v, dz = Z2[p] - z0v;
      MD2[p] = (dx * dx + dy * dy) + dz * dz;
      ILO[2 * p]     = 0xFFFFFFFFu - (unsigned)o0;
      ILO[2 * p + 1] = 0xFFFFFFFFu - (unsigned)o1;
    }
  }
#pragma unroll
  for (int off = 1; off < 64; off <<= 1) {
    mnx = fminf(mnx, __shfl_xor(mnx, off)); mxx = fmaxf(mxx, __shfl_xor(mxx, off));
    mny = fminf(mny, __shfl_xor(mny, off)); mxy = fmaxf(mxy, __shfl_xor(mxy, off));
    mnz = fminf(mnz, __shfl_xor(mnz, off)); mxz = fmaxf(mxz, __shfl_xor(mxz, off));
  }
  if (tid == 0) sampL[0] = 0;
  bool dirty = true;
  double W1 = 0.0, W2 = 0.0;   // wave's exact top-2 (valid in lane 63)
  int s = 1, it = 0;
#pragma unroll 1
  while (s < M) {
    if (dirty) {
      // element keys -> lane top-2 -> wave tuple reduce (lane 63)
      double k[E];
#pragma unroll
      for (int p = 0; p < P2; ++p) {
        k[2 * p] = __longlong_as_double((long long)(
            ((unsigned long long)__float_as_uint(MD2[p].x) << 32) | ILO[2 * p]));
        k[2 * p + 1] = __longlong_as_double((long long)(
            ((unsigned long long)__float_as_uint(MD2[p].y) << 32) | ILO[2 * p + 1]));
      }
      double A1 = dmax(k[0], k[1]), A2 = dmin(k[0], k[1]);
      double B1 = dmax(k[2], k[3]), B2 = dmin(k[2], k[3]);
      double C1 = dmax(k[4], k[5]), C2 = dmin(k[4], k[5]);
      double D1 = dmax(k[6], k[7]), D2 = dmin(k[6], k[7]);
      tup_comb(A1, A2, B1, B2); tup_comb(C1, C2, D1, D2); tup_comb(A1, A2, C1, C2);
      tup_stage<0x111, 0xF>(A1, A2);   // row_shr:1
      tup_stage<0x112, 0xF>(A1, A2);   // row_shr:2
      tup_stage<0x114, 0xF>(A1, A2);   // row_shr:4
      tup_stage<0x118, 0xF>(A1, A2);   // row_shr:8
      tup_stage<0x142, 0xA>(A1, A2);   // row_bcast:15 (rows 1,3)
      tup_stage<0x143, 0xC>(A1, A2);   // row_bcast:31 (rows 2,3)
      W1 = A1; W2 = A2;
    }
    const int pb = it & 1;
    if (lane == 63) ((double2*)kslots)[pb * 8 + wv] = make_double2(W1, W2);
    __syncthreads();
    // lane-parallel tuple slot read (slot and neighbor slot — both statically
    // conflict-free contiguous patterns), pre-combine, then 2-stage DPP tree
    // over disjoint slot windows -> exact global top-2 in every lane.
    const double2 tt = ((double2*)kslots)[pb * 8 + myslot];
    const double2 tn = ((double2*)kslots)[pb * 8 + (myslot ^ 1)];
    double T1 = tt.x, T2 = tt.y;
    tup_comb(T1, T2, tn.x, tn.y);
    tup_stage<0x4E, 0xF>(T1, T2);      // quad_perm [2,3,0,1]  (s -> s^2)
    tup_stage<0x124, 0xF>(T1, T2);     // row_ror:4            (s -> s^4)
    const unsigned long long g1b = (unsigned long long)__double_as_longlong(T1);
    const unsigned long long g2b = (unsigned long long)__double_as_longlong(T2);
    const int gi1 = (int)(0xFFFFFFFFu - (unsigned)g1b);
    const int gi2 = (int)(0xFFFFFFFFu - (unsigned)g2b);
    const float4 sp1 = pos4[gi1];
    const float4 sp2 = pos4[gi2];      // parallel uniform reads, one waitcnt
    // speculation check: does w1's update leave w2's key untouched?
    // d computed with the IDENTICAL rn op order the lane update uses.
    const float md2b = __uint_as_float((unsigned)(g2b >> 32));
    const float ddx = f_sub(sp2.x, sp1.x), ddy = f_sub(sp2.y, sp1.y),
                ddz = f_sub(sp2.z, sp1.z);
    const float dchk = f_add(f_add(f_mul(ddx, ddx), f_mul(ddy, ddy)), f_mul(ddz, ddz));
    const bool take2 = (s + 1 < M) && (dchk >= md2b);
    if (tid == 0) { sampL[s] = gi1; if (take2) sampL[s + 1] = gi2; }
    // per-wave AABB culls (conservative-exact: skip iff provably no-op)
    const float wmaxf = __uint_as_float((unsigned)__builtin_amdgcn_readlane(
        (int)(unsigned)((unsigned long long)__double_as_longlong(W1) >> 32), 63));
    const float m1x = fmaxf(fmaxf(f_sub(mnx, sp1.x), f_sub(sp1.x, mxx)), 0.f);
    const float m1y = fmaxf(fmaxf(f_sub(mny, sp1.y), f_sub(sp1.y, mxy)), 0.f);
    const float m1z = fmaxf(fmaxf(f_sub(mnz, sp1.z), f_sub(sp1.z, mxz)), 0.f);
    const bool u1 = sqnorm3(m1x, m1y, m1z) < wmaxf;
    const float m2x = fmaxf(fmaxf(f_sub(mnx, sp2.x), f_sub(sp2.x, mxx)), 0.f);
    const float m2y = fmaxf(fmaxf(f_sub(mny, sp2.y), f_sub(sp2.y, mxy)), 0.f);
    const float m2z = fmaxf(fmaxf(f_sub(mnz, sp2.z), f_sub(sp2.z, mxz)), 0.f);
    const bool u2 = take2 && (sqnorm3(m2x, m2y, m2z) < wmaxf);
    if (u1 | u2) {
      dirty = true;
      if (u1 & u2) {
        const v2f s1x = {sp1.x, sp1.x}, s1y = {sp1.y, sp1.y}, s1z = {sp1.z, sp1.z};
        const v2f s2x = {sp2.x, sp2.x}, s2y = {sp2.y, sp2.y}, s2z = {sp2.z, sp2.z};
#pragma unroll
        for (int p = 0; p < P2; ++p) {
          const v2f dx1 = X2[p] - s1x, dy1 = Y2[p] - s1y, dz1 = Z2[p] - s1z;
          const v2f d1 = (dx1 * dx1 + dy1 * dy1) + dz1 * dz1;
          MD2[p] = __builtin_elementwise_min(MD2[p], d1);
          const v2f dx2 = X2[p] - s2x, dy2 = Y2[p] - s2y, dz2 = Z2[p] - s2z;
          const v2f d2 = (dx2 * dx2 + dy2 * dy2) + dz2 * dz2;
          MD2[p] = __builtin_elementwise_min(MD2[p], d2);
        }
      } else {
        const float4 sp = u1 ? sp1 : sp2;
        const v2f sxv = {sp.x, sp.x}, syv = {sp.y, sp.y}, szv = {sp.z, sp.z};
#pragma unroll
        for (int p = 0; p < P2; ++p) {
          const v2f dx = X2[p] - sxv, dy = Y2[p] - syv, dz = Z2[p] - szv;
          const v2f d = (dx * dx + dy * dy) + dz * dz;
          MD2[p] = __builtin_elementwise_min(MD2[p], d);
        }
      }
    } else {
      dirty = false;
    }
    s += take2 ? 2 : 1;
    ++it;
  }
  __syncthreads();
  // bulk copy-out: indices + gathered positions, once
  for (int s2 = tid; s2 < M; s2 += THREADS) {
    const int g = sampL[s2];
    samp[s2] = g;
    const float4 sp2 = pos4[g];
    pos_out[3 * s2 + 0] = sp2.x;
    pos_out[3 * s2 + 1] = sp2.y;
    pos_out[3 * s2 + 2] = sp2.z;
  }
}

__device__ __forceinline__ float f4c(const float4& v, int c) {
  return c == 0 ? v.x : c == 1 ? v.y : c == 2 ? v.z : v.w;
}
__device__ __forceinline__ void fma4(float4& a, float v, const float4& w) {
  a.x += v * w.x; a.y += v * w.y; a.z += v * w.z; a.w += v * w.w;
}

// ---------------- PointNet edge MLP (2C+3 -> 32 -> relu -> 32, max over K, relu)
// (used by megaA / layer 1 only; layers 2-3 use the oct path below)
template<int K, int C>
__device__ void pn_compute(
    const float4* __restrict__ sW1, const float4* __restrict__ sW2,
    const float* __restrict__ sb1, const float* __restrict__ sb2,
    const float* __restrict__ P, const float* __restrict__ Hsrc,
    const int* __restrict__ hmap, int i, float xi, float yi, float zi,
    const int* kn, float* __restrict__ outrow)
{
  float4 abase[8];
#pragma unroll
  for (int o = 0; o < 8; ++o)
    abase[o] = make_float4(sb1[4 * o], sb1[4 * o + 1], sb1[4 * o + 2], sb1[4 * o + 3]);
  if constexpr (C == 1) {
    const float v = Hsrc[hmap ? hmap[i] : i];
#pragma unroll
    for (int o = 0; o < 8; ++o) fma4(abase[o], v, sW1[o]);
  } else {
    const int ri = hmap ? hmap[i] : i;
    const float4* Hi = (const float4*)(Hsrc + (size_t)ri * C);
#pragma unroll
    for (int c4 = 0; c4 < C / 4; ++c4) {
      const float4 hv = Hi[c4];
#pragma unroll
      for (int q = 0; q < 4; ++q) {
        const float v = f4c(hv, q);
#pragma unroll
        for (int o = 0; o < 8; ++o) fma4(abase[o], v, sW1[(4 * c4 + q) * 8 + o]);
      }
    }
  }
  float4 best[8];
#pragma unroll
  for (int o = 0; o < 8; ++o)
    best[o] = make_float4(-__builtin_inff(), -__builtin_inff(), -__builtin_inff(), -__builtin_inff());

  auto edge_pair = [&](int j0, int j1) {
    float4 a0[8], a1[8];
#pragma unroll
    for (int o = 0; o < 8; ++o) { a0[o] = abase[o]; a1[o] = abase[o]; }
    const float rx0 = P[j0 * 3] - xi, ry0 = P[j0 * 3 + 1] - yi, rz0 = P[j0 * 3 + 2] - zi;
    const float rx1 = P[j1 * 3] - xi, ry1 = P[j1 * 3 + 1] - yi, rz1 = P[j1 * 3 + 2] - zi;
    if constexpr (C == 1) {
      const float v0 = Hsrc[hmap ? hmap[j0] : j0], v1 = Hsrc[hmap ? hmap[j1] : j1];
#pragma unroll
      for (int o = 0; o < 8; ++o) {
        const float4 w = sW1[C * 8 + o];
        fma4(a0[o], v0, w); fma4(a1[o], v1, w);
      }
    } else {
      const int r0i = hmap ? hmap[j0] : j0, r1i = hmap ? hmap[j1] : j1;
      const float4* Hj0 = (const float4*)(Hsrc + (size_t)r0i * C);
      const float4* Hj1 = (const float4*)(Hsrc + (size_t)r1i * C);
#pragma unroll
      for (int c4 = 0; c4 < C / 4; ++c4) {
        const float4 h0 = Hj0[c4], h1 = Hj1[c4];
#pragma unroll
        for (int q = 0; q < 4; ++q) {
          const float v0 = f4c(h0, q), v1 = f4c(h1, q);
#pragma unroll
          for (int o = 0; o < 8; ++o) {
            const float4 w = sW1[(C + 4 * c4 + q) * 8 + o];
            fma4(a0[o], v0, w); fma4(a1[o], v1, w);
          }
        }
      }
    }
    const float r0[3] = {rx0, ry0, rz0}, r1[3] = {rx1, ry1, rz1};
#pragma unroll
    for (int r = 0; r < 3; ++r) {
#pragma unroll
      for (int o = 0; o < 8; ++o) {
        const float4 w = sW1[(2 * C + r) * 8 + o];
        fma4(a0[o], r0[r], w); fma4(a1[o], r1[r], w);
      }
    }
#pragma unroll
    for (int o = 0; o < 8; ++o) {
      a0[o].x = fmaxf(a0[o].x, 0.f); a0[o].y = fmaxf(a0[o].y, 0.f);
      a0[o].z = fmaxf(a0[o].z, 0.f); a0[o].w = fmaxf(a0[o].w, 0.f);
      a1[o].x = fmaxf(a1[o].x, 0.f); a1[o].y = fmaxf(a1[o].y, 0.f);
      a1[o].z = fmaxf(a1[o].z, 0.f); a1[o].w = fmaxf(a1[o].w, 0.f);
    }
#pragma unroll
    for (int hf = 0; hf < 2; ++hf) {
      float4 m0[4], m1[4];
#pragma unroll
      for (int o4 = 0; o4 < 4; ++o4) {
        const int c0 = 16 * hf + 4 * o4;
        m0[o4] = make_float4(sb2[c0], sb2[c0 + 1], sb2[c0 + 2], sb2[c0 + 3]);
        m1[o4] = m0[o4];
      }
#pragma unroll
      for (int c = 0; c < 32; ++c) {
        const float v0 = f4c(a0[c >> 2], c & 3), v1 = f4c(a1[c >> 2], c & 3);
#pragma unroll
        for (int o4 = 0; o4 < 4; ++o4) {
          const float4 w = sW2[c * 8 + hf * 4 + o4];
          fma4(m0[o4], v0, w); fma4(m1[o4], v1, w);
        }
      }
#pragma unroll
      for (int o4 = 0; o4 < 4; ++o4) {
        float4& bb = best[hf * 4 + o4];
        bb.x = fmaxf(bb.x, fmaxf(m0[o4].x, m1[o4].x));
        bb.y = fmaxf(bb.y, fmaxf(m0[o4].y, m1[o4].y));
        bb.z = fmaxf(bb.z, fmaxf(m0[o4].z, m1[o4].z));
        bb.w = fmaxf(bb.w, fmaxf(m0[o4].w, m1[o4].w));
      }
    }
  };

#pragma unroll
  for (int e = 0; e + 1 < K; e += 2) edge_pair(kn[e], kn[e + 1]);
  // K is even for layer 1 (K=6).

  float4* ho = (float4*)outrow;
#pragma unroll
  for (int o = 0; o < 8; ++o)
    ho[o] = make_float4(fmaxf(best[o].x, 0.0f), fmaxf(best[o].y, 0.0f),
                        fmaxf(best[o].z, 0.0f), fmaxf(best[o].w, 0.0f));
}

// ---------------- fused kNN + PN layer, one query per thread (layer 1 only).
template<int K, int NC, int C, int THREADS>
__device__ void fused_knn_pn(char* __restrict__ smem,
    const float* __restrict__ P, const float* __restrict__ Hsrc,
    const int* __restrict__ hmap,
    const float* __restrict__ W1, const float* __restrict__ b1,
    const float* __restrict__ W2, const float* __restrict__ b2,
    float* __restrict__ hout, int s)
{
  constexpr int CIN = 2 * C + 3;
  float4* tile = (float4*)smem;                       // [1024]
  float4* sW1 = (float4*)(smem + 16 * 1024);          // [CIN*8]
  float4* sW2 = sW1 + CIN * 8;                        // [32*8]
  float* sb1 = (float*)(sW2 + 32 * 8);
  float* sb2 = sb1 + 32;
  const int tid = threadIdx.x;
  for (int t = tid; t < CIN * 8; t += THREADS) sW1[t] = ((const float4*)W1)[t];
  for (int t = tid; t < 32 * 8; t += THREADS) sW2[t] = ((const float4*)W2)[t];
  if (tid < 32) { sb1[tid] = b1[tid]; sb2[tid] = b2[tid]; }

  const float xi = P[s * 3], yi = P[s * 3 + 1], zi = P[s * 3 + 2];
  const float ni = sqnorm3(xi, yi, zi);
  float bd[K]; int bj[K];
#pragma unroll
  for (int t = 0; t < K; ++t) { bd[t] = __builtin_inff(); bj[t] = 0; }
  for (int base = 0; base < NC; base += 1024) {
    __syncthreads();
    for (int t = tid; t < 1024; t += THREADS) {
      const float* q = P + (size_t)(base + t) * 3;
      const float x = q[0], y = q[1], z = q[2];
      tile[t] = make_float4(x, y, z, sqnorm3(x, y, z));
    }
    __syncthreads();
    // batch-8: issue 8 LDS reads + compute 8 distances, then the (rare) inserts.
#pragma unroll 1
    for (int t = 0; t < 1024; t += 8) {
      float dv[8];
#pragma unroll
      for (int u = 0; u < 8; ++u) {
        const float4 q = tile[t + u];
        const float dot = f_add(f_add(f_mul(xi, q.x), f_mul(yi, q.y)), f_mul(zi, q.z));
        dv[u] = f_sub(f_add(ni, q.w), f_mul(2.0f, dot));
      }
#pragma unroll
      for (int u = 0; u < 8; ++u) {
        if (dv[u] < bd[K - 1]) {      // strict < keeps earlier index on ties
          bd[K - 1] = dv[u]; bj[K - 1] = base + t + u;
#pragma unroll
          for (int r = K - 1; r > 0; --r) {
            if (bd[r] < bd[r - 1]) {
              float td = bd[r]; bd[r] = bd[r - 1]; bd[r - 1] = td;
              int   tj = bj[r]; bj[r] = bj[r - 1]; bj[r - 1] = tj;
            } else break;
          }
        }
      }
    }
  }
  pn_compute<K, C>(sW1, sW2, sb1, sb2, P, Hsrc, hmap, s, xi, yi, zi, bj,
                   hout + (size_t)s * 32);
}

// ---------------- OCT fused kNN + PN (layers 2 & 3, C=32): 8 lanes per query.
// Each lane scans a contiguous EIGHTH of the candidates (exact per-lane top-4
// by (d, idx)); lanes merge via 3 stages (xor1, xor2, xor4) of the verified
// bitonic CE network on packed u64 keys (order-mapped f32 bits || candidate
// idx) — keys are unique and merged-top-4 is associative over partitions, so
// the result reproduces jax.lax.top_k's (value, lower-index) tie-breaking
// bitwise, independent of the 8-way split. Then each lane computes ONE edge's
// MLP (K=4 -> lanes 4-7 duplicate edges 0-3; K=3 -> clamp; duplicates are
// idempotent under max) and a 3-stage shfl_xor butterfly max-aggregates.
// Tile is stored with a +1-float4 skew per eighth: region q starts at float4
// q*(RQ+1) -> bank 4q mod 32, all 8 distinct -> the 8 concurrent scan streams
// (each a same-address broadcast across its 8 query-groups) are statically
// bank-conflict-free.
template<int K, int NC>
__device__ void fused_knn_pn_oct(char* __restrict__ smem,
    const float* __restrict__ P, const float* __restrict__ Hsrc,
    const int* __restrict__ hmap,
    const float* __restrict__ W1, const float* __restrict__ b1,
    const float* __restrict__ W2, const float* __restrict__ b2,
    float* __restrict__ hout, int s, int q)
{
  constexpr int THREADS = 256;
  constexpr int RQ = NC / 8;          // candidates per lane
  constexpr int CIN = 67;             // 2*32+3
  float4* tile = (float4*)smem;                         // [NC + 8] (skewed)
  float4* sW1 = (float4*)(smem + 16 * (NC + 8));        // [CIN*8]
  float4* sW2 = sW1 + CIN * 8;                          // [32*8]
  float* sb1 = (float*)(sW2 + 32 * 8);
  float* sb2 = sb1 + 32;
  const int tid = threadIdx.x;

  for (int t = tid; t < NC; t += THREADS) {
    const float* c = P + (size_t)t * 3;
    const float x = c[0], y = c[1], z = c[2];
    tile[t + t / RQ] = make_float4(x, y, z, sqnorm3(x, y, z));
  }
  for (int t = tid; t < CIN * 8; t += THREADS) sW1[t] = ((const float4*)W1)[t];
  for (int t = tid; t < 32 * 8; t += THREADS) sW2[t] = ((const float4*)W2)[t];
  if (tid < 32) { sb1[tid] = b1[tid]; sb2[tid] = b2[tid]; }
  __syncthreads();

  const float4 qv = tile[s + s / RQ];     // exact copy of P row s (s < NC always)
  const float xi = qv.x, yi = qv.y, zi = qv.z, ni = qv.w;

  // prefetch this query's own h row into registers (independent of the scan)
  const int ri = hmap ? hmap[s] : s;
  float4 hi4[8];
  {
    const float4* Hi = (const float4*)(Hsrc + (size_t)ri * 32);
#pragma unroll
    for (int c4 = 0; c4 < 8; ++c4) hi4[c4] = Hi[c4];
  }

  float bd[4]; int bj[4];
#pragma unroll
  for (int t = 0; t < 4; ++t) { bd[t] = __builtin_inff(); bj[t] = 0; }
  const int sbase = q * (RQ + 1);
  // batch-8 scan: 8 LDS reads in flight, then the (rare) inserts in order.
#pragma unroll 1
  for (int t = 0; t < RQ; t += 8) {
    float dv[8];
#pragma unroll
    for (int u = 0; u < 8; ++u) {
      const float4 c = tile[sbase + t + u];
      const float dot = f_add(f_add(f_mul(xi, c.x), f_mul(yi, c.y)), f_mul(zi, c.z));
      dv[u] = f_sub(f_add(ni, c.w), f_mul(2.0f, dot));
    }
#pragma unroll
    for (int u = 0; u < 8; ++u) {
      if (dv[u] < bd[3]) {              // strict < keeps earlier index on ties
        bd[3] = dv[u]; bj[3] = q * RQ + t + u;
#pragma unroll
        for (int r = 3; r > 0; --r) {
          if (bd[r] < bd[r - 1]) {
            float td = bd[r]; bd[r] = bd[r - 1]; bd[r - 1] = td;
            int   tj = bj[r]; bj[r] = bj[r - 1]; bj[r - 1] = tj;
          } else break;
        }
      }
    }
  }
  // pack (d, idx) -> u64 key, order-preserving for all finite f32 (incl. negatives)
  unsigned long long a0, a1, a2, a3;
  {
    auto mk = [](float d, int j) {
      unsigned u = __float_as_uint(d);
      u ^= (unsigned)((int)u >> 31) | 0x80000000u;
      return ((unsigned long long)u << 32) | (unsigned)j;
    };
    a0 = mk(bd[0], bj[0]); a1 = mk(bd[1], bj[1]);
    a2 = mk(bd[2], bj[2]); a3 = mk(bd[3], bj[3]);
  }
  // 3 merge stages (xor 1, 2, 4); both partners compute identical results at
  // every stage, so all 8 lanes end with the identical global top-4.
#pragma unroll
  for (int st = 1; st <= 4; st <<= 1) {
    const unsigned long long b0 = __shfl_xor(a0, st), b1_ = __shfl_xor(a1, st),
                             b2_ = __shfl_xor(a2, st), b3_ = __shfl_xor(a3, st);
    const unsigned long long t0 = u64min(a0, b3_), t1 = u64min(a1, b2_),
                             t2 = u64min(a2, b1_), t3 = u64min(a3, b0);
    const unsigned long long u0 = u64min(t0, t2), u2 = u64max(t0, t2),
                             u1 = u64min(t1, t3), u3 = u64max(t1, t3);
    a0 = u64min(u0, u1); a1 = u64max(u0, u1);
    a2 = u64min(u2, u3); a3 = u64max(u2, u3);
  }
  const int eq = q & 3;
  const int e = (eq < K) ? eq : (K - 1);   // lanes 4-7 duplicate (idempotent)
  const unsigned long long ke = (e == 0) ? a0 : (e == 1) ? a1 : (e == 2) ? a2 : a3;
  const int jn = (int)(unsigned)ke;     // this lane's edge neighbor

  // ---- one edge MLP (same accumulation order as the scalar path: b1, h_i, h_j, rel)
  const int rj = hmap ? hmap[jn] : jn;
  // prefetch neighbor h row before the FMA chains so the global load is in flight
  float4 hj4[8];
  {
    const float4* Hj = (const float4*)(Hsrc + (size_t)rj * 32);
#pragma unroll
    for (int c4 = 0; c4 < 8; ++c4) hj4[c4] = Hj[c4];
  }
  float4 acc[8];
#pragma unroll
  for (int o = 0; o < 8; ++o)
    acc[o] = make_float4(sb1[4 * o], sb1[4 * o + 1], sb1[4 * o + 2], sb1[4 * o + 3]);
#pragma unroll
  for (int c4 = 0; c4 < 8; ++c4) {
    const float4 hv = hi4[c4];
#pragma unroll
    for (int t = 0; t < 4; ++t) {
      const float v = f4c(hv, t);
#pragma unroll
      for (int o = 0; o < 8; ++o) fma4(acc[o], v, sW1[(4 * c4 + t) * 8 + o]);
    }
  }
#pragma unroll
  for (int c4 = 0; c4 < 8; ++c4) {
    const float4 hv = hj4[c4];
#pragma unroll
    for (int t = 0; t < 4; ++t) {
      const float v = f4c(hv, t);
#pragma unroll
      for (int o = 0; o < 8; ++o) fma4(acc[o], v, sW1[(32 + 4 * c4 + t) * 8 + o]);
    }
  }
  const float4 cj = tile[jn + jn / RQ];
  const float r3[3] = {cj.x - xi, cj.y - yi, cj.z - zi};
#pragma unroll
  for (int r = 0; r < 3; ++r)
#pragma unroll
    for (int o = 0; o < 8; ++o) fma4(acc[o], r3[r], sW1[(64 + r) * 8 + o]);
#pragma unroll
  for (int o = 0; o < 8; ++o) {
    acc[o].x = fmaxf(acc[o].x, 0.f); acc[o].y = fmaxf(acc[o].y, 0.f);
    acc[o].z = fmaxf(acc[o].z, 0.f); acc[o].w = fmaxf(acc[o].w, 0.f);
  }
  float4 m[8];
#pragma unroll
  for (int o = 0; o < 8; ++o)
    m[o] = make_float4(sb2[4 * o], sb2[4 * o + 1], sb2[4 * o + 2], sb2[4 * o + 3]);
#pragma unroll
  for (int c = 0; c < 32; ++c) {
    const float v = f4c(acc[c >> 2], c & 3);
#pragma unroll
    for (int o = 0; o < 8; ++o) fma4(m[o], v, sW2[c * 8 + o]);
  }
  // 8-lane butterfly max over the K edges (max is order-independent; no NaNs)
#pragma unroll
  for (int o = 0; o < 8; ++o) {
    float4 v = m[o];
#pragma unroll
    for (int st = 1; st <= 4; st <<= 1) {
      v.x = fmaxf(v.x, __shfl_xor(v.x, st)); v.y = fmaxf(v.y, __shfl_xor(v.y, st));
      v.z = fmaxf(v.z, __shfl_xor(v.z, st)); v.w = fmaxf(v.w, __shfl_xor(v.w, st));
    }
    m[o] = v;
  }
  // lane q writes float4 q of the output row (8 lanes cover all 32 floats)
  float4* ho = (float4*)(hout + (size_t)s * 32);
  {
    const float4 v0 = m[q];
    ho[q] = make_float4(fmaxf(v0.x, 0.f), fmaxf(v0.y, 0.f),
                        fmaxf(v0.z, 0.f), fmaxf(v0.w, 0.f));
  }
}

// ---------------- megaA: fps1 rides alongside fused knn1+pn1 (all 4096 queries)
__global__ __launch_bounds__(512) void megaA(
    const float* __restrict__ x, const float* __restrict__ pos,
    const float* __restrict__ W11, const float* __restrict__ b11,
    const float* __restrict__ W12, const float* __restrict__ b12,
    int* __restrict__ samp1, float* __restrict__ pos2, float* __restrict__ h1full)
{
  // fps needs 18*NP1 + 4*NP2 + 32 + 256 = 82208 B
  __shared__ __align__(16) char smem[82240];
  if (blockIdx.x < BATCH) {
    const int b = blockIdx.x;
    fps_block<NP1, NP2>(smem, pos + (size_t)b * NP1 * 3, samp1 + b * NP2,
                        pos2 + (size_t)b * NP2 * 3);
  } else {
    const int id = blockIdx.x - BATCH;
    const int b = id >> 3;
    const int s = (id & 7) * 512 + threadIdx.x;
    fused_knn_pn<6, NP1, 1, 512>(smem, pos + (size_t)b * NP1 * 3, x + (size_t)b * NP1,
                                 nullptr, W11, b11, W12, b12,
                                 h1full + (size_t)b * NP1 * 32, s);
  }
}

// ---------------- megaB: layer 2, NO fps (fps2 == identity — proof in journal).
// 8 lanes per query; 32 blocks per batch -> 512 blocks (2 blocks/CU).
__global__ __launch_bounds__(256) void megaB(
    const float* __restrict__ pos2, const int* __restrict__ samp1,
    const float* __restrict__ h1full,
    const float* __restrict__ W21, const float* __restrict__ b21,
    const float* __restrict__ W22, const float* __restrict__ b22,
    float* __restrict__ h2out)
{
  __shared__ __align__(16) char smem[(2048 + 8) * 16 + 67 * 8 * 16 + 32 * 8 * 16 + 256];
  const int b = blockIdx.x >> 5;
  const int s = ((blockIdx.x & 31) << 5) + (threadIdx.x >> 3);
  const int q = threadIdx.x & 7;
  fused_knn_pn_oct<4, NP2>(smem, pos2 + (size_t)b * NP2 * 3,
                           h1full + (size_t)b * NP1 * 32, samp1 + b * NP2,
                           W21, b21, W22, b22, h2out + (size_t)b * NP3 * 32, s, q);
}

// ---------------- megaC: layer 3 on pos3 = pos2 rows 0..1023, h3 = h2out rows.
__global__ __launch_bounds__(256) void megaC(
    const float* __restrict__ pos2, const float* __restrict__ h2out,
    const float* __restrict__ W31, const float* __restrict__ b31,
    const float* __restrict__ W32, const float* __restrict__ b32,
    float* __restrict__ h3full)
{
  __shared__ __align__(16) char smem[(1024 + 8) * 16 + 67 * 8 * 16 + 32 * 8 * 16 + 256];
  const int b = blockIdx.x >> 5;
  const int s = ((blockIdx.x & 31) << 5) + (threadIdx.x >> 3);
  const int q = threadIdx.x & 7;
  // candidates = first 1024 rows of pos2 (contiguous prefix of the row-major array)
  fused_knn_pn_oct<3, NP3>(smem, pos2 + (size_t)b * NP2 * 3,
                           h2out + (size_t)b * NP3 * 32, nullptr,
                           W31, b31, W32, b32, h3full + (size_t)b * NP3 * 32, s, q);
}

// ---------------- global max pool over NP3 points + final linear 32->10
__global__ __launch_bounds__(256) void final_kernel(
    const float* __restrict__ h, const float* __restrict__ Wr,
    const float* __restrict__ br, float* __restrict__ out)
{
  __shared__ float red[8][32];
  __shared__ float g[32];
  const int b = blockIdx.x;
  const int c = threadIdx.x & 31, grp = threadIdx.x >> 5;
  const float* H = h + (size_t)b * NP3 * 32;
  float m = -__builtin_inff();
  for (int r = grp; r < NP3; r += 8) m = fmaxf(m, H[r * 32 + c]);
  red[grp][c] = m;
  __syncthreads();
  if (threadIdx.x < 32) {
    float v = red[0][c];
#pragma unroll
    for (int w = 1; w < 8; ++w) v = fmaxf(v, red[w][c]);
    g[c] = v;
  }
  __syncthreads();
  if (threadIdx.x < 10) {
    float v = br[threadIdx.x];
#pragma unroll
    for (int cc = 0; cc < 32; ++cc) v += g[cc] * Wr[cc * 10 + threadIdx.x];
    out[b * 10 + threadIdx.x] = v;
  }
}

extern "C" void kernel_launch(void* const* d_in, const int* in_sizes, int n_in,
                              void* d_out, int out_size, void* d_ws, size_t ws_size,
                              hipStream_t stream) {
  const float* x   = (const float*)d_in[0];
  const float* pos = (const float*)d_in[1];
  const float* W11 = (const float*)d_in[2];
  const float* b11 = (const float*)d_in[3];
  const float* W12 = (const float*)d_in[4];
  const float* b12 = (const float*)d_in[5];
  const float* W21 = (const float*)d_in[6];
  const float* b21 = (const float*)d_in[7];
  const float* W22 = (const float*)d_in[8];
  const float* b22 = (const float*)d_in[9];
  const float* W31 = (const float*)d_in[10];
  const float* b31 = (const float*)d_in[11];
  const float* W32 = (const float*)d_in[12];
  const float* b32 = (const float*)d_in[13];
  const float* Wr  = (const float*)d_in[14];
  const float* br  = (const float*)d_in[15];
  float* out = (float*)d_out;

  char* p = (char*)d_ws;
  auto alloc = [&](size_t bytes) {
    char* r = p; p += (bytes + 255) & ~(size_t)255; return r;
  };
  int*   samp1  = (int*)  alloc(sizeof(int)   * BATCH * NP2);
  float* pos2   = (float*)alloc(sizeof(float) * BATCH * NP2 * 3);
  float* h1full = (float*)alloc(sizeof(float) * BATCH * NP1 * 32);  // 8 MB
  float* h2out  = (float*)alloc(sizeof(float) * BATCH * NP3 * 32);  // 2 MB
  float* h3full = (float*)alloc(sizeof(float) * BATCH * NP3 * 32);  // 2 MB

  megaA<<<BATCH + BATCH * (NP1 / 512), 512, 0, stream>>>(     // 16 + 128
      x, pos, W11, b11, W12, b12, samp1, pos2, h1full);
  megaB<<<BATCH * 32, 256, 0, stream>>>(                      // 512
      pos2, samp1, h1full, W21, b21, W22, b22, h2out);
  megaC<<<BATCH * 32, 256, 0, stream>>>(                      // 512
      pos2, h2out, W31, b31, W32, b32, h3full);
  final_kernel<<<BATCH, 256, 0, stream>>>(h3full, Wr, br, out);
}

// Round 12
// 1290.256 us; speedup vs baseline: 1.0235x; 1.0235x over previous
//
#include <hip/hip_runtime.h>

#define BATCH 16
#define NP1 4096
#define NP2 2048
#define NP3 1024

typedef float v2f __attribute__((ext_vector_type(2)));

// IEEE ops that the compiler may NOT contract/reorder — used for every distance
// that feeds a discrete decision (kNN membership, FPS argmax). Order matches the
// reference: norms (x*x+y*y)+z*z ; knn d = (ni+nj) - 2*dot ; fps d = (dx^2+dy^2)+dz^2.
__device__ __forceinline__ float f_add(float a, float b) { return __fadd_rn(a, b); }
__device__ __forceinline__ float f_mul(float a, float b) { return __fmul_rn(a, b); }
__device__ __forceinline__ float f_sub(float a, float b) { return __fsub_rn(a, b); }
__device__ __forceinline__ float sqnorm3(float x, float y, float z) {
  return f_add(f_add(f_mul(x, x), f_mul(y, y)), f_mul(z, z));
}

__device__ __forceinline__ unsigned long long u64max(unsigned long long a,
                                                     unsigned long long b) {
  return a > b ? a : b;
}
__device__ __forceinline__ unsigned long long u64min(unsigned long long a,
                                                     unsigned long long b) {
  return a < b ? a : b;
}
__device__ __forceinline__ double dmax(double a, double b) { return __builtin_fmax(a, b); }
__device__ __forceinline__ double dmin(double a, double b) { return __builtin_fmin(a, b); }

template<int CTRL, int RMASK>
__device__ __forceinline__ unsigned long long dpp_u64(unsigned long long k) {
  const int lo = __builtin_amdgcn_update_dpp(0, (int)(unsigned)k, CTRL, RMASK, 0xF, true);
  const int hi = __builtin_amdgcn_update_dpp(0, (int)(unsigned)(k >> 32), CTRL, RMASK, 0xF, true);
  return ((unsigned long long)(unsigned)hi << 32) | (unsigned)lo;
}
template<int CTRL, int RMASK>
__device__ __forceinline__ double dpp_dbl(double v) {
  return __longlong_as_double(
      (long long)dpp_u64<CTRL, RMASK>((unsigned long long)__double_as_longlong(v)));
}

// FPS keys: u64 {dist_bits(32) | ILO(32)} reinterpreted as f64. dist_bits ≤
// 0x40400000 and sign bit 0 -> positive f64, never NaN/Inf, so u64 order ==
// f64 order exactly and v_max_f64/v_min_f64 implement exact key compares.
// ILO = ~gi resolves dist-ties to the LOWEST original index (jnp.argmax).
// All keys are > 0 (ILO never 0), so 0.0 is the reduce identity.

// Exact top-2 tuple combine: (a1,a2) := top2({a1,a2} ∪ {b1,b2}).
// Requires a1>=a2, b1>=b2 (and (0,0) acts as identity for positive keys).
__device__ __forceinline__ void tup_comb(double& a1, double& a2, double b1, double b2) {
  const double hi = dmax(a1, b1);
  const double lo = dmin(a1, b1);
  a2 = dmax(lo, dmax(a2, b2));
  a1 = hi;
}
template<int CTRL, int RMASK>
__device__ __forceinline__ void tup_stage(double& a1, double& a2) {
  const double b1 = dpp_dbl<CTRL, RMASK>(a1);
  const double b2 = dpp_dbl<CTRL, RMASK>(a2);
  tup_comb(a1, a2, b1, b2);
}

// ---------------- FPS device block: exact replica of the reference scan, with
// exact 2-per-step speculation (round-3 form: the cheap "untouched" check).
// Per step: global top-2 (G1,G2) from per-wave exact top-2 tuple slots.
// w1=G1 selected; if d_rn(w2,w1) >= min_d(w2) (updates only lower keys; keys
// unique) then w2=G2 is provably the NEXT argmax too -> commit both, apply both
// min-updates sequentially (exact). All DPP reduce trees combine disjoint
// lane/slot windows, so tuple top-2 stays exact.
// Slot tree: each lane reads slot(lane&7) AND slot((lane&7)^1) — 8 distinct
// CONTIGUOUS 16B addresses each (statically bank-conflict-free; the
// data-dependent gather/staging variants of rounds 6/7/9 all regressed) —
// pre-combines, then a 2-stage DPP tuple tree (s->s^2, s->s^4) yields the
// exact global top-2 in every lane.
// fps2 of the network is the identity permutation (journal proof).
// NOTE: this FPS structure is at its measured practical floor (rounds 4-9
// probes); do not restructure without strong new evidence.
template<int N, int M>
__device__ void fps_block(char* __restrict__ smem, const float* __restrict__ P,
                          int* __restrict__ samp, float* __restrict__ pos_out)
{
#pragma clang fp contract(off)
  constexpr int THREADS = 512;
  constexpr int E = N / THREADS;
  constexpr int P2 = E / 2;
  float4* pos4 = (float4*)smem;                                   // [N] by orig idx
  unsigned short* ord = (unsigned short*)(smem + 16 * N);         // [N]
  int* sampL = (int*)(smem + 18 * N);                             // [M]
  unsigned* cursor = (unsigned*)(smem + 18 * N + 4 * M);          // [8]
  double* kslots = (double*)(smem + 18 * N + 4 * M + 32);         // [2][8] double2
  const int tid = threadIdx.x;
  const int lane = tid & 63, wv = tid >> 6;
  const int myslot = lane & 7;
  if (tid < 8) cursor[tid] = 0u;
  __syncthreads();
  int oct[E];
#pragma unroll
  for (int e = 0; e < E; ++e) {
    const int t = e * THREADS + tid;
    const float x = P[t * 3], y = P[t * 3 + 1], z = P[t * 3 + 2];
    pos4[t] = make_float4(x, y, z, 0.f);
    oct[e] = (x > 0.5f ? 1 : 0) | (y > 0.5f ? 2 : 0) | (z > 0.5f ? 4 : 0);
    atomicAdd(&cursor[oct[e]], 1u);
  }
  __syncthreads();
  if (tid == 0) {
    unsigned run = 0;
#pragma unroll
    for (int o = 0; o < 8; ++o) { const unsigned c = cursor[o]; cursor[o] = run; run += c; }
  }
  __syncthreads();
#pragma unroll
  for (int e = 0; e < E; ++e) {
    const unsigned d = atomicAdd(&cursor[oct[e]], 1u);
    ord[d] = (unsigned short)(e * THREADS + tid);
  }
  __syncthreads();
  const float4 p0 = pos4[0];
  const float x0 = p0.x, y0 = p0.y, z0 = p0.z;
  v2f X2[P2], Y2[P2], Z2[P2], MD2[P2];
  unsigned ILO[E];
  float mnx = 1e30f, mny = 1e30f, mnz = 1e30f;
  float mxx = -1e30f, mxy = -1e30f, mxz = -1e30f;
  {
    const v2f x0v = {x0, x0}, y0v = {y0, y0}, z0v = {z0, z0};
#pragma unroll
    for (int p = 0; p < P2; ++p) {
      const int q0 = wv * (64 * E) + (2 * p) * 64 + lane;  // wave-contiguous sorted range
      const int o0 = ord[q0], o1 = ord[q0 + 64];
      const float4 a0 = pos4[o0], a1 = pos4[o1];
      X2[p] = (v2f){a0.x, a1.x}; Y2[p] = (v2f){a0.y, a1.y}; Z2[p] = (v2f){a0.z, a1.z};
      mnx = fminf(mnx, fminf(a0.x, a1.x)); mxx = fmaxf(mxx, fmaxf(a0.x, a1.x));
      mny = fminf(mny, fminf(a0.y, a1.y)); mxy = fmaxf(mxy, fmaxf(a0.y, a1.y));
      mnz = fminf(mnz, fminf(a0.z, a1.z)); mxz = fmaxf(mxz, fmaxf(a0.z, a1.z));
      const v2f dx = X2[p] - x0v, dy = Y2[p] - y0v, dz = Z2[p] - z0v;
      MD2[p] = (dx * dx + dy * dy) + dz * dz;
      ILO[2 * p]     = 0xFFFFFFFFu - (unsigned)o0;
      ILO[2 * p + 1] = 0xFFFFFFFFu - (unsigned)o1;
    }
  }
#pragma unroll
  for (int off = 1; off < 64; off <<= 1) {
    mnx = fminf(mnx, __shfl_xor(mnx, off)); mxx = fmaxf(mxx, __shfl_xor(mxx, off));
    mny = fminf(mny, __shfl_xor(mny, off)); mxy = fmaxf(mxy, __shfl_xor(mxy, off));
    mnz = fminf(mnz, __shfl_xor(mnz, off)); mxz = fmaxf(mxz, __shfl_xor(mxz, off));
  }
  if (tid == 0) sampL[0] = 0;
  bool dirty = true;
  double W1 = 0.0, W2 = 0.0;   // wave's exact top-2 (valid in lane 63)
  int s = 1, it = 0;
#pragma unroll 1
  while (s < M) {
    if (dirty) {
      // element keys -> lane top-2 -> wave tuple reduce (lane 63)
      double k[E];
#pragma unroll
      for (int p = 0; p < P2; ++p) {
        k[2 * p] = __longlong_as_double((long long)(
            ((unsigned long long)__float_as_uint(MD2[p].x) << 32) | ILO[2 * p]));
        k[2 * p + 1] = __longlong_as_double((long long)(
            ((unsigned long long)__float_as_uint(MD2[p].y) << 32) | ILO[2 * p + 1]));
      }
      double A1 = dmax(k[0], k[1]), A2 = dmin(k[0], k[1]);
      double B1 = dmax(k[2], k[3]), B2 = dmin(k[2], k[3]);
      double C1 = dmax(k[4], k[5]), C2 = dmin(k[4], k[5]);
      double D1 = dmax(k[6], k[7]), D2 = dmin(k[6], k[7]);
      tup_comb(A1, A2, B1, B2); tup_comb(C1, C2, D1, D2); tup_comb(A1, A2, C1, C2);
      tup_stage<0x111, 0xF>(A1, A2);   // row_shr:1
      tup_stage<0x112, 0xF>(A1, A2);   // row_shr:2
      tup_stage<0x114, 0xF>(A1, A2);   // row_shr:4
      tup_stage<0x118, 0xF>(A1, A2);   // row_shr:8
      tup_stage<0x142, 0xA>(A1, A2);   // row_bcast:15 (rows 1,3)
      tup_stage<0x143, 0xC>(A1, A2);   // row_bcast:31 (rows 2,3)
      W1 = A1; W2 = A2;
    }
    const int pb = it & 1;
    if (lane == 63) ((double2*)kslots)[pb * 8 + wv] = make_double2(W1, W2);
    __syncthreads();
    // lane-parallel tuple slot read (slot and neighbor slot — both statically
    // conflict-free contiguous patterns), pre-combine, then 2-stage DPP tree
    // over disjoint slot windows -> exact global top-2 in every lane.
    const double2 tt = ((double2*)kslots)[pb * 8 + myslot];
    const double2 tn = ((double2*)kslots)[pb * 8 + (myslot ^ 1)];
    double T1 = tt.x, T2 = tt.y;
    tup_comb(T1, T2, tn.x, tn.y);
    tup_stage<0x4E, 0xF>(T1, T2);      // quad_perm [2,3,0,1]  (s -> s^2)
    tup_stage<0x124, 0xF>(T1, T2);     // row_ror:4            (s -> s^4)
    const unsigned long long g1b = (unsigned long long)__double_as_longlong(T1);
    const unsigned long long g2b = (unsigned long long)__double_as_longlong(T2);
    const int gi1 = (int)(0xFFFFFFFFu - (unsigned)g1b);
    const int gi2 = (int)(0xFFFFFFFFu - (unsigned)g2b);
    const float4 sp1 = pos4[gi1];
    const float4 sp2 = pos4[gi2];      // parallel uniform reads, one waitcnt
    // speculation check: does w1's update leave w2's key untouched?
    // d computed with the IDENTICAL rn op order the lane update uses.
    const float md2b = __uint_as_float((unsigned)(g2b >> 32));
    const float ddx = f_sub(sp2.x, sp1.x), ddy = f_sub(sp2.y, sp1.y),
                ddz = f_sub(sp2.z, sp1.z);
    const float dchk = f_add(f_add(f_mul(ddx, ddx), f_mul(ddy, ddy)), f_mul(ddz, ddz));
    const bool take2 = (s + 1 < M) && (dchk >= md2b);
    if (tid == 0) { sampL[s] = gi1; if (take2) sampL[s + 1] = gi2; }
    // per-wave AABB culls (conservative-exact: skip iff provably no-op)
    const float wmaxf = __uint_as_float((unsigned)__builtin_amdgcn_readlane(
        (int)(unsigned)((unsigned long long)__double_as_longlong(W1) >> 32), 63));
    const float m1x = fmaxf(fmaxf(f_sub(mnx, sp1.x), f_sub(sp1.x, mxx)), 0.f);
    const float m1y = fmaxf(fmaxf(f_sub(mny, sp1.y), f_sub(sp1.y, mxy)), 0.f);
    const float m1z = fmaxf(fmaxf(f_sub(mnz, sp1.z), f_sub(sp1.z, mxz)), 0.f);
    const bool u1 = sqnorm3(m1x, m1y, m1z) < wmaxf;
    const float m2x = fmaxf(fmaxf(f_sub(mnx, sp2.x), f_sub(sp2.x, mxx)), 0.f);
    const float m2y = fmaxf(fmaxf(f_sub(mny, sp2.y), f_sub(sp2.y, mxy)), 0.f);
    const float m2z = fmaxf(fmaxf(f_sub(mnz, sp2.z), f_sub(sp2.z, mxz)), 0.f);
    const bool u2 = take2 && (sqnorm3(m2x, m2y, m2z) < wmaxf);
    if (u1 | u2) {
      dirty = true;
      if (u1 & u2) {
        const v2f s1x = {sp1.x, sp1.x}, s1y = {sp1.y, sp1.y}, s1z = {sp1.z, sp1.z};
        const v2f s2x = {sp2.x, sp2.x}, s2y = {sp2.y, sp2.y}, s2z = {sp2.z, sp2.z};
#pragma unroll
        for (int p = 0; p < P2; ++p) {
          const v2f dx1 = X2[p] - s1x, dy1 = Y2[p] - s1y, dz1 = Z2[p] - s1z;
          const v2f d1 = (dx1 * dx1 + dy1 * dy1) + dz1 * dz1;
          MD2[p] = __builtin_elementwise_min(MD2[p], d1);
          const v2f dx2 = X2[p] - s2x, dy2 = Y2[p] - s2y, dz2 = Z2[p] - s2z;
          const v2f d2 = (dx2 * dx2 + dy2 * dy2) + dz2 * dz2;
          MD2[p] = __builtin_elementwise_min(MD2[p], d2);
        }
      } else {
        const float4 sp = u1 ? sp1 : sp2;
        const v2f sxv = {sp.x, sp.x}, syv = {sp.y, sp.y}, szv = {sp.z, sp.z};
#pragma unroll
        for (int p = 0; p < P2; ++p) {
          const v2f dx = X2[p] - sxv, dy = Y2[p] - syv, dz = Z2[p] - szv;
          const v2f d = (dx * dx + dy * dy) + dz * dz;
          MD2[p] = __builtin_elementwise_min(MD2[p], d);
        }
      }
    } else {
      dirty = false;
    }
    s += take2 ? 2 : 1;
    ++it;
  }
  __syncthreads();
  // bulk copy-out: indices + gathered positions, once
  for (int s2 = tid; s2 < M; s2 += THREADS) {
    const int g = sampL[s2];
    samp[s2] = g;
    const float4 sp2 = pos4[g];
    pos_out[3 * s2 + 0] = sp2.x;
    pos_out[3 * s2 + 1] = sp2.y;
    pos_out[3 * s2 + 2] = sp2.z;
  }
}

__device__ __forceinline__ float f4c(const float4& v, int c) {
  return c == 0 ? v.x : c == 1 ? v.y : c == 2 ? v.z : v.w;
}
__device__ __forceinline__ void fma4(float4& a, float v, const float4& w) {
  a.x += v * w.x; a.y += v * w.y; a.z += v * w.z; a.w += v * w.w;
}

// ---------------- PointNet edge MLP (2C+3 -> 32 -> relu -> 32, max over K, relu)
// (used by megaA / layer 1 only; layers 2-3 use the quad path below)
template<int K, int C>
__device__ void pn_compute(
    const float4* __restrict__ sW1, const float4* __restrict__ sW2,
    const float* __restrict__ sb1, const float* __restrict__ sb2,
    const float* __restrict__ P, const float* __restrict__ Hsrc,
    const int* __restrict__ hmap, int i, float xi, float yi, float zi,
    const int* kn, float* __restrict__ outrow)
{
  float4 abase[8];
#pragma unroll
  for (int o = 0; o < 8; ++o)
    abase[o] = make_float4(sb1[4 * o], sb1[4 * o + 1], sb1[4 * o + 2], sb1[4 * o + 3]);
  if constexpr (C == 1) {
    const float v = Hsrc[hmap ? hmap[i] : i];
#pragma unroll
    for (int o = 0; o < 8; ++o) fma4(abase[o], v, sW1[o]);
  } else {
    const int ri = hmap ? hmap[i] : i;
    const float4* Hi = (const float4*)(Hsrc + (size_t)ri * C);
#pragma unroll
    for (int c4 = 0; c4 < C / 4; ++c4) {
      const float4 hv = Hi[c4];
#pragma unroll
      for (int q = 0; q < 4; ++q) {
        const float v = f4c(hv, q);
#pragma unroll
        for (int o = 0; o < 8; ++o) fma4(abase[o], v, sW1[(4 * c4 + q) * 8 + o]);
      }
    }
  }
  float4 best[8];
#pragma unroll
  for (int o = 0; o < 8; ++o)
    best[o] = make_float4(-__builtin_inff(), -__builtin_inff(), -__builtin_inff(), -__builtin_inff());

  auto edge_pair = [&](int j0, int j1) {
    float4 a0[8], a1[8];
#pragma unroll
    for (int o = 0; o < 8; ++o) { a0[o] = abase[o]; a1[o] = abase[o]; }
    const float rx0 = P[j0 * 3] - xi, ry0 = P[j0 * 3 + 1] - yi, rz0 = P[j0 * 3 + 2] - zi;
    const float rx1 = P[j1 * 3] - xi, ry1 = P[j1 * 3 + 1] - yi, rz1 = P[j1 * 3 + 2] - zi;
    if constexpr (C == 1) {
      const float v0 = Hsrc[hmap ? hmap[j0] : j0], v1 = Hsrc[hmap ? hmap[j1] : j1];
#pragma unroll
      for (int o = 0; o < 8; ++o) {
        const float4 w = sW1[C * 8 + o];
        fma4(a0[o], v0, w); fma4(a1[o], v1, w);
      }
    } else {
      const int r0i = hmap ? hmap[j0] : j0, r1i = hmap ? hmap[j1] : j1;
      const float4* Hj0 = (const float4*)(Hsrc + (size_t)r0i * C);
      const float4* Hj1 = (const float4*)(Hsrc + (size_t)r1i * C);
#pragma unroll
      for (int c4 = 0; c4 < C / 4; ++c4) {
        const float4 h0 = Hj0[c4], h1 = Hj1[c4];
#pragma unroll
        for (int q = 0; q < 4; ++q) {
          const float v0 = f4c(h0, q), v1 = f4c(h1, q);
#pragma unroll
          for (int o = 0; o < 8; ++o) {
            const float4 w = sW1[(C + 4 * c4 + q) * 8 + o];
            fma4(a0[o], v0, w); fma4(a1[o], v1, w);
          }
        }
      }
    }
    const float r0[3] = {rx0, ry0, rz0}, r1[3] = {rx1, ry1, rz1};
#pragma unroll
    for (int r = 0; r < 3; ++r) {
#pragma unroll
      for (int o = 0; o < 8; ++o) {
        const float4 w = sW1[(2 * C + r) * 8 + o];
        fma4(a0[o], r0[r], w); fma4(a1[o], r1[r], w);
      }
    }
#pragma unroll
    for (int o = 0; o < 8; ++o) {
      a0[o].x = fmaxf(a0[o].x, 0.f); a0[o].y = fmaxf(a0[o].y, 0.f);
      a0[o].z = fmaxf(a0[o].z, 0.f); a0[o].w = fmaxf(a0[o].w, 0.f);
      a1[o].x = fmaxf(a1[o].x, 0.f); a1[o].y = fmaxf(a1[o].y, 0.f);
      a1[o].z = fmaxf(a1[o].z, 0.f); a1[o].w = fmaxf(a1[o].w, 0.f);
    }
#pragma unroll
    for (int hf = 0; hf < 2; ++hf) {
      float4 m0[4], m1[4];
#pragma unroll
      for (int o4 = 0; o4 < 4; ++o4) {
        const int c0 = 16 * hf + 4 * o4;
        m0[o4] = make_float4(sb2[c0], sb2[c0 + 1], sb2[c0 + 2], sb2[c0 + 3]);
        m1[o4] = m0[o4];
      }
#pragma unroll
      for (int c = 0; c < 32; ++c) {
        const float v0 = f4c(a0[c >> 2], c & 3), v1 = f4c(a1[c >> 2], c & 3);
#pragma unroll
        for (int o4 = 0; o4 < 4; ++o4) {
          const float4 w = sW2[c * 8 + hf * 4 + o4];
          fma4(m0[o4], v0, w); fma4(m1[o4], v1, w);
        }
      }
#pragma unroll
      for (int o4 = 0; o4 < 4; ++o4) {
        float4& bb = best[hf * 4 + o4];
        bb.x = fmaxf(bb.x, fmaxf(m0[o4].x, m1[o4].x));
        bb.y = fmaxf(bb.y, fmaxf(m0[o4].y, m1[o4].y));
        bb.z = fmaxf(bb.z, fmaxf(m0[o4].z, m1[o4].z));
        bb.w = fmaxf(bb.w, fmaxf(m0[o4].w, m1[o4].w));
      }
    }
  };

#pragma unroll
  for (int e = 0; e + 1 < K; e += 2) edge_pair(kn[e], kn[e + 1]);
  // K is even for layer 1 (K=6).

  float4* ho = (float4*)outrow;
#pragma unroll
  for (int o = 0; o < 8; ++o)
    ho[o] = make_float4(fmaxf(best[o].x, 0.0f), fmaxf(best[o].y, 0.0f),
                        fmaxf(best[o].z, 0.0f), fmaxf(best[o].w, 0.0f));
}

// ---------------- fused kNN + PN layer, one query per thread (layer 1 only).
template<int K, int NC, int C, int THREADS>
__device__ void fused_knn_pn(char* __restrict__ smem,
    const float* __restrict__ P, const float* __restrict__ Hsrc,
    const int* __restrict__ hmap,
    const float* __restrict__ W1, const float* __restrict__ b1,
    const float* __restrict__ W2, const float* __restrict__ b2,
    float* __restrict__ hout, int s)
{
  constexpr int CIN = 2 * C + 3;
  float4* tile = (float4*)smem;                       // [1024]
  float4* sW1 = (float4*)(smem + 16 * 1024);          // [CIN*8]
  float4* sW2 = sW1 + CIN * 8;                        // [32*8]
  float* sb1 = (float*)(sW2 + 32 * 8);
  float* sb2 = sb1 + 32;
  const int tid = threadIdx.x;
  for (int t = tid; t < CIN * 8; t += THREADS) sW1[t] = ((const float4*)W1)[t];
  for (int t = tid; t < 32 * 8; t += THREADS) sW2[t] = ((const float4*)W2)[t];
  if (tid < 32) { sb1[tid] = b1[tid]; sb2[tid] = b2[tid]; }

  const float xi = P[s * 3], yi = P[s * 3 + 1], zi = P[s * 3 + 2];
  const float ni = sqnorm3(xi, yi, zi);
  float bd[K]; int bj[K];
#pragma unroll
  for (int t = 0; t < K; ++t) { bd[t] = __builtin_inff(); bj[t] = 0; }
  for (int base = 0; base < NC; base += 1024) {
    __syncthreads();
    for (int t = tid; t < 1024; t += THREADS) {
      const float* q = P + (size_t)(base + t) * 3;
      const float x = q[0], y = q[1], z = q[2];
      tile[t] = make_float4(x, y, z, sqnorm3(x, y, z));
    }
    __syncthreads();
    // batch-8: issue 8 LDS reads + compute 8 distances, then the (rare) inserts.
#pragma unroll 1
    for (int t = 0; t < 1024; t += 8) {
      float dv[8];
#pragma unroll
      for (int u = 0; u < 8; ++u) {
        const float4 q = tile[t + u];
        const float dot = f_add(f_add(f_mul(xi, q.x), f_mul(yi, q.y)), f_mul(zi, q.z));
        dv[u] = f_sub(f_add(ni, q.w), f_mul(2.0f, dot));
      }
#pragma unroll
      for (int u = 0; u < 8; ++u) {
        if (dv[u] < bd[K - 1]) {      // strict < keeps earlier index on ties
          bd[K - 1] = dv[u]; bj[K - 1] = base + t + u;
#pragma unroll
          for (int r = K - 1; r > 0; --r) {
            if (bd[r] < bd[r - 1]) {
              float td = bd[r]; bd[r] = bd[r - 1]; bd[r - 1] = td;
              int   tj = bj[r]; bj[r] = bj[r - 1]; bj[r - 1] = tj;
            } else break;
          }
        }
      }
    }
  }
  pn_compute<K, C>(sW1, sW2, sb1, sb2, P, Hsrc, hmap, s, xi, yi, zi, bj,
                   hout + (size_t)s * 32);
}

// ---------------- QUAD fused kNN + PN (layers 2 & 3, C=32): 4 lanes per query.
// Each lane scans a contiguous quarter of the candidates (exact per-lane top-4 by
// (d, idx)); lanes merge via a bitonic CE network on packed u64 keys
// (order-mapped f32 bits || candidate idx) — keys are unique, so the merged top-4
// reproduces jax.lax.top_k's (value, lower-index) tie-breaking bitwise. Then each
// lane computes ONE edge's MLP (K=4 -> 1:1; K=3 -> lane 3 duplicates edge K-1,
// idempotent under max) and a 2-stage shfl_xor butterfly max-aggregates.
// Tile is stored with a +1-float4 skew per quarter so the 4 concurrent scan
// streams hit disjoint LDS bank groups (region q starts at bank 4q).
// NOTE: 4 lanes / 16 blocks-per-batch is the measured optimum — the 8-lane /
// 32-block variant (round 11) doubled per-block tile+weight staging and lost.
template<int K, int NC>
__device__ void fused_knn_pn_quad(char* __restrict__ smem,
    const float* __restrict__ P, const float* __restrict__ Hsrc,
    const int* __restrict__ hmap,
    const float* __restrict__ W1, const float* __restrict__ b1,
    const float* __restrict__ W2, const float* __restrict__ b2,
    float* __restrict__ hout, int s, int q)
{
  constexpr int THREADS = 256;
  constexpr int RQ = NC / 4;          // candidates per lane
  constexpr int CIN = 67;             // 2*32+3
  float4* tile = (float4*)smem;                         // [NC + 4] (skewed)
  float4* sW1 = (float4*)(smem + 16 * (NC + 4));        // [CIN*8]
  float4* sW2 = sW1 + CIN * 8;                          // [32*8]
  float* sb1 = (float*)(sW2 + 32 * 8);
  float* sb2 = sb1 + 32;
  const int tid = threadIdx.x;

  for (int t = tid; t < NC; t += THREADS) {
    const float* c = P + (size_t)t * 3;
    const float x = c[0], y = c[1], z = c[2];
    tile[t + t / RQ] = make_float4(x, y, z, sqnorm3(x, y, z));
  }
  for (int t = tid; t < CIN * 8; t += THREADS) sW1[t] = ((const float4*)W1)[t];
  for (int t = tid; t < 32 * 8; t += THREADS) sW2[t] = ((const float4*)W2)[t];
  if (tid < 32) { sb1[tid] = b1[tid]; sb2[tid] = b2[tid]; }
  __syncthreads();

  const float4 qv = tile[s + s / RQ];     // exact copy of P row s (s < NC always)
  const float xi = qv.x, yi = qv.y, zi = qv.z, ni = qv.w;

  // prefetch this query's own h row into registers (independent of the scan)
  const int ri = hmap ? hmap[s] : s;
  float4 hi4[8];
  {
    const float4* Hi = (const float4*)(Hsrc + (size_t)ri * 32);
#pragma unroll
    for (int c4 = 0; c4 < 8; ++c4) hi4[c4] = Hi[c4];
  }

  float bd[4]; int bj[4];
#pragma unroll
  for (int t = 0; t < 4; ++t) { bd[t] = __builtin_inff(); bj[t] = 0; }
  const int sbase = q * (RQ + 1);
  // batch-8 scan: 8 LDS reads in flight, then the (rare) inserts in order.
#pragma unroll 1
  for (int t = 0; t < RQ; t += 8) {
    float dv[8];
#pragma unroll
    for (int u = 0; u < 8; ++u) {
      const float4 c = tile[sbase + t + u];
      const float dot = f_add(f_add(f_mul(xi, c.x), f_mul(yi, c.y)), f_mul(zi, c.z));
      dv[u] = f_sub(f_add(ni, c.w), f_mul(2.0f, dot));
    }
#pragma unroll
    for (int u = 0; u < 8; ++u) {
      if (dv[u] < bd[3]) {              // strict < keeps earlier index on ties
        bd[3] = dv[u]; bj[3] = q * RQ + t + u;
#pragma unroll
        for (int r = 3; r > 0; --r) {
          if (bd[r] < bd[r - 1]) {
            float td = bd[r]; bd[r] = bd[r - 1]; bd[r - 1] = td;
            int   tj = bj[r]; bj[r] = bj[r - 1]; bj[r - 1] = tj;
          } else break;
        }
      }
    }
  }
  // pack (d, idx) -> u64 key, order-preserving for all finite f32 (incl. negatives)
  unsigned long long a0, a1, a2, a3;
  {
    auto mk = [](float d, int j) {
      unsigned u = __float_as_uint(d);
      u ^= (unsigned)((int)u >> 31) | 0x80000000u;
      return ((unsigned long long)u << 32) | (unsigned)j;
    };
    a0 = mk(bd[0], bj[0]); a1 = mk(bd[1], bj[1]);
    a2 = mk(bd[2], bj[2]); a3 = mk(bd[3], bj[3]);
  }
  // stage 1: merge with pair partner (xor 1); both partners compute identical result
  {
    const unsigned long long b0 = __shfl_xor(a0, 1), b1_ = __shfl_xor(a1, 1),
                             b2_ = __shfl_xor(a2, 1), b3_ = __shfl_xor(a3, 1);
    const unsigned long long t0 = u64min(a0, b3_), t1 = u64min(a1, b2_),
                             t2 = u64min(a2, b1_), t3 = u64min(a3, b0);
    const unsigned long long u0 = u64min(t0, t2), u2 = u64max(t0, t2),
                             u1 = u64min(t1, t3), u3 = u64max(t1, t3);
    a0 = u64min(u0, u1); a1 = u64max(u0, u1);
    a2 = u64min(u2, u3); a3 = u64max(u2, u3);
  }
  // stage 2: merge across pairs (xor 2) -> global top-4 in all 4 lanes
  {
    const unsigned long long b0 = __shfl_xor(a0, 2), b1_ = __shfl_xor(a1, 2),
                             b2_ = __shfl_xor(a2, 2), b3_ = __shfl_xor(a3, 2);
    const unsigned long long t0 = u64min(a0, b3_), t1 = u64min(a1, b2_),
                             t2 = u64min(a2, b1_), t3 = u64min(a3, b0);
    const unsigned long long u0 = u64min(t0, t2), u2 = u64max(t0, t2),
                             u1 = u64min(t1, t3), u3 = u64max(t1, t3);
    a0 = u64min(u0, u1); a1 = u64max(u0, u1);
    a2 = u64min(u2, u3); a3 = u64max(u2, u3);
  }
  const int e = (q < K) ? q : (K - 1);
  const unsigned long long ke = (e == 0) ? a0 : (e == 1) ? a1 : (e == 2) ? a2 : a3;
  const int jn = (int)(unsigned)ke;     // this lane's edge neighbor

  // ---- one edge MLP (same accumulation order as the scalar path: b1, h_i, h_j, rel)
  const int rj = hmap ? hmap[jn] : jn;
  // prefetch neighbor h row before the FMA chains so the global load is in flight
  float4 hj4[8];
  {
    const float4* Hj = (const float4*)(Hsrc + (size_t)rj * 32);
#pragma unroll
    for (int c4 = 0; c4 < 8; ++c4) hj4[c4] = Hj[c4];
  }
  float4 acc[8];
#pragma unroll
  for (int o = 0; o < 8; ++o)
    acc[o] = make_float4(sb1[4 * o], sb1[4 * o + 1], sb1[4 * o + 2], sb1[4 * o + 3]);
#pragma unroll
  for (int c4 = 0; c4 < 8; ++c4) {
    const float4 hv = hi4[c4];
#pragma unroll
    for (int t = 0; t < 4; ++t) {
      const float v = f4c(hv, t);
#pragma unroll
      for (int o = 0; o < 8; ++o) fma4(acc[o], v, sW1[(4 * c4 + t) * 8 + o]);
    }
  }
#pragma unroll
  for (int c4 = 0; c4 < 8; ++c4) {
    const float4 hv = hj4[c4];
#pragma unroll
    for (int t = 0; t < 4; ++t) {
      const float v = f4c(hv, t);
#pragma unroll
      for (int o = 0; o < 8; ++o) fma4(acc[o], v, sW1[(32 + 4 * c4 + t) * 8 + o]);
    }
  }
  const float4 cj = tile[jn + jn / RQ];
  const float r3[3] = {cj.x - xi, cj.y - yi, cj.z - zi};
#pragma unroll
  for (int r = 0; r < 3; ++r)
#pragma unroll
    for (int o = 0; o < 8; ++o) fma4(acc[o], r3[r], sW1[(64 + r) * 8 + o]);
#pragma unroll
  for (int o = 0; o < 8; ++o) {
    acc[o].x = fmaxf(acc[o].x, 0.f); acc[o].y = fmaxf(acc[o].y, 0.f);
    acc[o].z = fmaxf(acc[o].z, 0.f); acc[o].w = fmaxf(acc[o].w, 0.f);
  }
  float4 m[8];
#pragma unroll
  for (int o = 0; o < 8; ++o)
    m[o] = make_float4(sb2[4 * o], sb2[4 * o + 1], sb2[4 * o + 2], sb2[4 * o + 3]);
#pragma unroll
  for (int c = 0; c < 32; ++c) {
    const float v = f4c(acc[c >> 2], c & 3);
#pragma unroll
    for (int o = 0; o < 8; ++o) fma4(m[o], v, sW2[c * 8 + o]);
  }
  // quad butterfly max over the K edges (max is order-independent; no NaNs)
#pragma unroll
  for (int o = 0; o < 8; ++o) {
    float4 v = m[o];
    v.x = fmaxf(v.x, __shfl_xor(v.x, 1)); v.y = fmaxf(v.y, __shfl_xor(v.y, 1));
    v.z = fmaxf(v.z, __shfl_xor(v.z, 1)); v.w = fmaxf(v.w, __shfl_xor(v.w, 1));
    v.x = fmaxf(v.x, __shfl_xor(v.x, 2)); v.y = fmaxf(v.y, __shfl_xor(v.y, 2));
    v.z = fmaxf(v.z, __shfl_xor(v.z, 2)); v.w = fmaxf(v.w, __shfl_xor(v.w, 2));
    m[o] = v;
  }
  float4* ho = (float4*)(hout + (size_t)s * 32);
  {
    const float4 v0 = m[2 * q], v1 = m[2 * q + 1];
    ho[2 * q] = make_float4(fmaxf(v0.x, 0.f), fmaxf(v0.y, 0.f),
                            fmaxf(v0.z, 0.f), fmaxf(v0.w, 0.f));
    ho[2 * q + 1] = make_float4(fmaxf(v1.x, 0.f), fmaxf(v1.y, 0.f),
                                fmaxf(v1.z, 0.f), fmaxf(v1.w, 0.f));
  }
}

// ---------------- megaA: fps1 rides alongside fused knn1+pn1 (all 4096 queries)
__global__ __launch_bounds__(512) void megaA(
    const float* __restrict__ x, const float* __restrict__ pos,
    const float* __restrict__ W11, const float* __restrict__ b11,
    const float* __restrict__ W12, const float* __restrict__ b12,
    int* __restrict__ samp1, float* __restrict__ pos2, float* __restrict__ h1full)
{
  // fps needs 18*NP1 + 4*NP2 + 32 + 256 = 82208 B
  __shared__ __align__(16) char smem[82240];
  if (blockIdx.x < BATCH) {
    const int b = blockIdx.x;
    fps_block<NP1, NP2>(smem, pos + (size_t)b * NP1 * 3, samp1 + b * NP2,
                        pos2 + (size_t)b * NP2 * 3);
  } else {
    const int id = blockIdx.x - BATCH;
    const int b = id >> 3;
    const int s = (id & 7) * 512 + threadIdx.x;
    fused_knn_pn<6, NP1, 1, 512>(smem, pos + (size_t)b * NP1 * 3, x + (size_t)b * NP1,
                                 nullptr, W11, b11, W12, b12,
                                 h1full + (size_t)b * NP1 * 32, s);
  }
}

// ---------------- megaB: layer 2, NO fps (fps2 == identity — proof in journal).
// 4 lanes per query; 16 blocks per batch -> 256 blocks (full CU coverage).
__global__ __launch_bounds__(256) void megaB(
    const float* __restrict__ pos2, const int* __restrict__ samp1,
    const float* __restrict__ h1full,
    const float* __restrict__ W21, const float* __restrict__ b21,
    const float* __restrict__ W22, const float* __restrict__ b22,
    float* __restrict__ h2out)
{
  __shared__ __align__(16) char smem[(2048 + 4) * 16 + 67 * 8 * 16 + 32 * 8 * 16 + 256];
  const int b = blockIdx.x >> 4;
  const int s = ((blockIdx.x & 15) << 6) + (threadIdx.x >> 2);
  const int q = threadIdx.x & 3;
  fused_knn_pn_quad<4, NP2>(smem, pos2 + (size_t)b * NP2 * 3,
                            h1full + (size_t)b * NP1 * 32, samp1 + b * NP2,
                            W21, b21, W22, b22, h2out + (size_t)b * NP3 * 32, s, q);
}

// ---------------- megaC: layer 3 on pos3 = pos2 rows 0..1023, h3 = h2out rows.
__global__ __launch_bounds__(256) void megaC(
    const float* __restrict__ pos2, const float* __restrict__ h2out,
    const float* __restrict__ W31, const float* __restrict__ b31,
    const float* __restrict__ W32, const float* __restrict__ b32,
    float* __restrict__ h3full)
{
  __shared__ __align__(16) char smem[(1024 + 4) * 16 + 67 * 8 * 16 + 32 * 8 * 16 + 256];
  const int b = blockIdx.x >> 4;
  const int s = ((blockIdx.x & 15) << 6) + (threadIdx.x >> 2);
  const int q = threadIdx.x & 3;
  // candidates = first 1024 rows of pos2 (contiguous prefix of the row-major array)
  fused_knn_pn_quad<3, NP3>(smem, pos2 + (size_t)b * NP2 * 3,
                            h2out + (size_t)b * NP3 * 32, nullptr,
                            W31, b31, W32, b32, h3full + (size_t)b * NP3 * 32, s, q);
}

// ---------------- global max pool over NP3 points + final linear 32->10
__global__ __launch_bounds__(256) void final_kernel(
    const float* __restrict__ h, const float* __restrict__ Wr,
    const float* __restrict__ br, float* __restrict__ out)
{
  __shared__ float red[8][32];
  __shared__ float g[32];
  const int b = blockIdx.x;
  const int c = threadIdx.x & 31, grp = threadIdx.x >> 5;
  const float* H = h + (size_t)b * NP3 * 32;
  float m = -__builtin_inff();
  for (int r = grp; r < NP3; r += 8) m = fmaxf(m, H[r * 32 + c]);
  red[grp][c] = m;
  __syncthreads();
  if (threadIdx.x < 32) {
    float v = red[0][c];
#pragma unroll
    for (int w = 1; w < 8; ++w) v = fmaxf(v, red[w][c]);
    g[c] = v;
  }
  __syncthreads();
  if (threadIdx.x < 10) {
    float v = br[threadIdx.x];
#pragma unroll
    for (int cc = 0; cc < 32; ++cc) v += g[cc] * Wr[cc * 10 + threadIdx.x];
    out[b * 10 + threadIdx.x] = v;
  }
}

extern "C" void kernel_launch(void* const* d_in, const int* in_sizes, int n_in,
                              void* d_out, int out_size, void* d_ws, size_t ws_size,
                              hipStream_t stream) {
  const float* x   = (const float*)d_in[0];
  const float* pos = (const float*)d_in[1];
  const float* W11 = (const float*)d_in[2];
  const float* b11 = (const float*)d_in[3];
  const float* W12 = (const float*)d_in[4];
  const float* b12 = (const float*)d_in[5];
  const float* W21 = (const float*)d_in[6];
  const float* b21 = (const float*)d_in[7];
  const float* W22 = (const float*)d_in[8];
  const float* b22 = (const float*)d_in[9];
  const float* W31 = (const float*)d_in[10];
  const float* b31 = (const float*)d_in[11];
  const float* W32 = (const float*)d_in[12];
  const float* b32 = (const float*)d_in[13];
  const float* Wr  = (const float*)d_in[14];
  const float* br  = (const float*)d_in[15];
  float* out = (float*)d_out;

  char* p = (char*)d_ws;
  auto alloc = [&](size_t bytes) {
    char* r = p; p += (bytes + 255) & ~(size_t)255; return r;
  };
  int*   samp1  = (int*)  alloc(sizeof(int)   * BATCH * NP2);
  float* pos2   = (float*)alloc(sizeof(float) * BATCH * NP2 * 3);
  float* h1full = (float*)alloc(sizeof(float) * BATCH * NP1 * 32);  // 8 MB
  float* h2out  = (float*)alloc(sizeof(float) * BATCH * NP3 * 32);  // 2 MB
  float* h3full = (float*)alloc(sizeof(float) * BATCH * NP3 * 32);  // 2 MB

  megaA<<<BATCH + BATCH * (NP1 / 512), 512, 0, stream>>>(     // 16 + 128
      x, pos, W11, b11, W12, b12, samp1, pos2, h1full);
  megaB<<<BATCH * 16, 256, 0, stream>>>(                      // 256
      pos2, samp1, h1full, W21, b21, W22, b22, h2out);
  megaC<<<BATCH * 16, 256, 0, stream>>>(                      // 256
      pos2, h2out, W31, b31, W32, b32, h3full);
  final_kernel<<<BATCH, 256, 0, stream>>>(h3full, Wr, br, out);
}